// Round 1
// 396.292 us; speedup vs baseline: 1.0303x; 1.0303x over previous
//
#include <hip/hip_runtime.h>

#define C_IMG 512
#define C_PT  256
#define IMG_H 48
#define IMG_W 160
#define HWPIX (IMG_H * IMG_W)

#define MP   64     // points per block (M tile)
#define BK   64     // K chunk
#define SPAD 72     // LDS row pitch in bf16 (64 + 8 pad)

typedef short bf16x8 __attribute__((ext_vector_type(8)));
typedef float f32x4  __attribute__((ext_vector_type(4)));

static __device__ __forceinline__ unsigned short f2bf(float f) {
    unsigned u = __float_as_uint(f);
    u += 0x7fffu + ((u >> 16) & 1u);   // RNE
    return (unsigned short)(u >> 16);
}
static __device__ __forceinline__ unsigned pack2(float lo, float hi) {
    return (unsigned)f2bf(lo) | ((unsigned)f2bf(hi) << 16);
}
static __device__ __forceinline__ float bflo(unsigned v) { return __uint_as_float(v << 16); }
static __device__ __forceinline__ float bfhi(unsigned v) { return __uint_as_float(v & 0xffff0000u); }

// ---------------- transpose (B,C,H,W) f32 -> (B,H*W,C) bf16 ----------------
// v2: 64 channels per block, each thread writes 2 packed channels (u32) so
// every wave store is a full 128B cache line.
__global__ __launch_bounds__(256)
void transpose_kernel(const float* __restrict__ img, unsigned short* __restrict__ imgT) {
    __shared__ float tile[64][33];
    const int b   = blockIdx.z;
    const int hw0 = blockIdx.x * 32;
    const int c0  = blockIdx.y * 64;
    const int tx  = threadIdx.x;      // 0..31
    const int ty  = threadIdx.y;      // 0..7
    const float* src = img + (size_t)b * C_IMG * HWPIX;
    #pragma unroll
    for (int i = 0; i < 64; i += 8)
        tile[ty + i][tx] = src[(size_t)(c0 + ty + i) * HWPIX + hw0 + tx];
    __syncthreads();
    unsigned* dst = (unsigned*)(imgT + (size_t)b * HWPIX * C_IMG);
    #pragma unroll
    for (int i = 0; i < 32; i += 8) {
        const int hw = ty + i;
        dst[(size_t)(hw0 + hw) * (C_IMG / 2) + (c0 >> 1) + tx] =
            pack2(tile[2 * tx][hw], tile[2 * tx + 1][hw]);
    }
}

// ---------------- align_w f32 [C_PT][C_IMG] -> bf16 same layout ----------------
__global__ __launch_bounds__(256)
void cvt_w_kernel(const float* __restrict__ alw, unsigned short* __restrict__ alwT) {
    const int i = (blockIdx.x * 256 + threadIdx.x) * 8;
    const float4 a = *(const float4*)(alw + i);
    const float4 b = *(const float4*)(alw + i + 4);
    uint4 o;
    o.x = pack2(a.x, a.y); o.y = pack2(a.z, a.w);
    o.z = pack2(b.x, b.y); o.w = pack2(b.z, b.w);
    *(uint4*)(alwT + i) = o;
}

// ---------------- gather helpers (issue-early / commit-late split) ----------------
static __device__ __forceinline__ void gather_issue(
    const unsigned short* __restrict__ ib, const int* co, int cb, uint4* g)
{
    #pragma unroll
    for (int c = 0; c < 4; ++c) {
        g[2 * c]     = *(const uint4*)(ib + co[c] + cb);
        g[2 * c + 1] = *(const uint4*)(ib + co[c] + cb + 8);
    }
}
static __device__ __forceinline__ void gather_commit(
    unsigned short* __restrict__ dst, const uint4* g, const float* cw)
{
    #pragma unroll
    for (int h = 0; h < 2; ++h) {
        const unsigned* u0 = (const unsigned*)&g[0 + h];
        const unsigned* u1 = (const unsigned*)&g[2 + h];
        const unsigned* u2 = (const unsigned*)&g[4 + h];
        const unsigned* u3 = (const unsigned*)&g[6 + h];
        uint4 ov; unsigned* op = (unsigned*)&ov;
        #pragma unroll
        for (int wI = 0; wI < 4; ++wI) {
            const float vlo = cw[0]*bflo(u0[wI]) + cw[1]*bflo(u1[wI])
                            + cw[2]*bflo(u2[wI]) + cw[3]*bflo(u3[wI]);
            const float vhi = cw[0]*bfhi(u0[wI]) + cw[1]*bfhi(u1[wI])
                            + cw[2]*bfhi(u2[wI]) + cw[3]*bfhi(u3[wI]);
            op[wI] = pack2(vlo, vhi);
        }
        *(uint4*)(dst + h * 8) = ov;
    }
}

// ---------------- fused gather + GEMM + epilogue (bf16 imgT + bf16 alwT) ----------------
__global__ __launch_bounds__(256, 3)
void fused_trans_kernel(const float* __restrict__ pf,
                        const float* __restrict__ centers,
                        const unsigned short* __restrict__ imgT,
                        const unsigned short* __restrict__ alwT,
                        const float* __restrict__ P2,
                        const float* __restrict__ R0,
                        const float* __restrict__ Tr,
                        const float* __restrict__ alb,
                        const int*   __restrict__ bidx,
                        float* __restrict__ out,
                        int n)
{
    __shared__ float          sWg[MP][4];
    __shared__ int            sOf[MP][4];
    __shared__ unsigned short sS[2][MP][SPAD];   // double-buffered sampled tile

    const int tid = threadIdx.x;
    const int pt0 = blockIdx.x * MP;

    // ---- per-point projection (threads 0..63) ----
    if (tid < MP) {
        const int p = pt0 + tid;
        float w[4] = {0.f, 0.f, 0.f, 0.f};
        int   o[4] = {0, 0, 0, 0};
        if (p < n) {
            const float cx = centers[p * 3 + 0];
            const float cy = centers[p * 3 + 1];
            const float cz = centers[p * 3 + 2];
            const int   b  = bidx[p];
            const float* tr = Tr + b * 16;
            const float c0 = tr[0]*cx + tr[1]*cy + tr[2]*cz + tr[3];
            const float c1 = tr[4]*cx + tr[5]*cy + tr[6]*cz + tr[7];
            const float c2 = tr[8]*cx + tr[9]*cy + tr[10]*cz + tr[11];
            const float c3 = tr[12]*cx + tr[13]*cy + tr[14]*cz + tr[15];
            const float* r0 = R0 + b * 16;
            const float e0 = r0[0]*c0 + r0[1]*c1 + r0[2]*c2 + r0[3]*c3;
            const float e1 = r0[4]*c0 + r0[5]*c1 + r0[6]*c2 + r0[7]*c3;
            const float e2 = r0[8]*c0 + r0[9]*c1 + r0[10]*c2 + r0[11]*c3;
            const float e3 = r0[12]*c0 + r0[13]*c1 + r0[14]*c2 + r0[15]*c3;
            const float* p2 = P2 + b * 12;
            const float ix = p2[0]*e0 + p2[1]*e1 + p2[2]*e2  + p2[3]*e3;
            const float iy = p2[4]*e0 + p2[5]*e1 + p2[6]*e2  + p2[7]*e3;
            const float iz = p2[8]*e0 + p2[9]*e1 + p2[10]*e2 + p2[11]*e3;
            const float depth = fmaxf(iz, 1e-5f);
            const float u = ix / depth;
            const float v = iy / depth;
            const bool valid = (iz > 0.f) && (u >= 0.f) && (u < (float)IMG_W)
                                         && (v >= 0.f) && (v < (float)IMG_H);
            const float x0f = floorf(u), y0f = floorf(v);
            const float wx1 = u - x0f, wx0 = 1.f - wx1;
            const float wy1 = v - y0f, wy0 = 1.f - wy1;
            const float cwv[4] = {wx0 * wy0, wx1 * wy0, wx0 * wy1, wx1 * wy1};
            #pragma unroll
            for (int j = 0; j < 4; ++j) {
                const float xf = x0f + (float)(j & 1);
                const float yf = y0f + (float)(j >> 1);
                const bool inb = (xf >= 0.f) && (xf <= (float)(IMG_W - 1))
                              && (yf >= 0.f) && (yf <= (float)(IMG_H - 1));
                const int xc = (int)fminf(fmaxf(xf, 0.f), (float)(IMG_W - 1));
                const int yc = (int)fminf(fmaxf(yf, 0.f), (float)(IMG_H - 1));
                w[j] = (valid && inb) ? cwv[j] : 0.f;
                o[j] = ((b * IMG_H + yc) * IMG_W + xc) * C_IMG;
            }
        }
        #pragma unroll
        for (int j = 0; j < 4; ++j) { sWg[tid][j] = w[j]; sOf[tid][j] = o[j]; }
    }

    f32x4 acc[4][4];
    #pragma unroll
    for (int i = 0; i < 4; ++i)
        #pragma unroll
        for (int j = 0; j < 4; ++j)
            acc[i][j] = (f32x4){0.f, 0.f, 0.f, 0.f};

    const int lane = tid & 63;
    const int wid  = tid >> 6;
    const int l15  = lane & 15;
    const int quad = lane >> 4;
    const int sp   = tid >> 2;   // staging: point index
    const int ssub = tid & 3;    // staging: 16-channel sub-chunk

    __syncthreads();

    // hoist per-point gather params out of the K-loop (constant across ck)
    float cw[4]; int co[4];
    #pragma unroll
    for (int j = 0; j < 4; ++j) { cw[j] = sWg[sp][j]; co[j] = sOf[sp][j]; }
    const int cbase = ssub * 16;

    // per-thread base into bf16 align_w: row = out-channel, col = k
    const unsigned short* bwp = alwT + (size_t)(wid * 64 + l15) * C_IMG + quad * 8;

    // prologue: stage chunk 0 into buffer 0
    {
        uint4 g0[8];
        gather_issue(imgT, co, cbase, g0);
        gather_commit(&sS[0][sp][cbase], g0, cw);
    }
    __syncthreads();

    #pragma unroll
    for (int ck = 0; ck < C_IMG / BK; ++ck) {
        const int cur = ck & 1;
        uint4 gn[8];
        if (ck < C_IMG / BK - 1)
            gather_issue(imgT, co, (ck + 1) * BK + cbase, gn);   // loads in flight over MFMA

        #pragma unroll
        for (int kk = 0; kk < 2; ++kk) {
            bf16x8 bfr[4], af[4];
            #pragma unroll
            for (int nt = 0; nt < 4; ++nt)
                bfr[nt] = *(const bf16x8*)(bwp + nt * 16 * C_IMG + ck * BK + kk * 32);
            #pragma unroll
            for (int mt = 0; mt < 4; ++mt)
                af[mt] = *(const bf16x8*)&sS[cur][mt * 16 + l15][kk * 32 + quad * 8];
            #pragma unroll
            for (int mt = 0; mt < 4; ++mt)
                #pragma unroll
                for (int nt = 0; nt < 4; ++nt)
                    acc[mt][nt] = __builtin_amdgcn_mfma_f32_16x16x32_bf16(
                        af[mt], bfr[nt], acc[mt][nt], 0, 0, 0);
        }

        if (ck < C_IMG / BK - 1)
            gather_commit(&sS[cur ^ 1][sp][cbase], gn, cw);      // write-late into other buffer
        __syncthreads();
    }

    // ---- epilogue: out = point_feat + bias + acc ----
    // C/D layout (16x16): col = lane&15 (n), row = quad*4 + reg (m)
    #pragma unroll
    for (int mt = 0; mt < 4; ++mt) {
        #pragma unroll
        for (int r = 0; r < 4; ++r) {
            const int p = pt0 + mt * 16 + quad * 4 + r;
            if (p < n) {
                #pragma unroll
                for (int nt = 0; nt < 4; ++nt) {
                    const int nc = wid * 64 + nt * 16 + l15;
                    const size_t idx = (size_t)p * C_PT + nc;
                    out[idx] = pf[idx] + alb[nc] + acc[mt][nt][r];
                }
            }
        }
    }
}

// ---------------- fallback: original single-kernel path (no workspace) ----------------
__global__ __launch_bounds__(256)
void fused_fallback_kernel(const float* __restrict__ pf,
                           const float* __restrict__ centers,
                           const float* __restrict__ img,
                           const float* __restrict__ P2,
                           const float* __restrict__ R0,
                           const float* __restrict__ Tr,
                           const float* __restrict__ alw,
                           const float* __restrict__ alb,
                           const int*   __restrict__ bidx,
                           float* __restrict__ out,
                           int n)
{
    __shared__ float          sWg[MP][4];
    __shared__ int            sOf[MP][4];
    __shared__ unsigned short sS[MP][SPAD];
    __shared__ unsigned short sW[C_PT][SPAD];

    const int tid = threadIdx.x;
    const int pt0 = blockIdx.x * MP;

    if (tid < MP) {
        const int p = pt0 + tid;
        float w[4] = {0.f, 0.f, 0.f, 0.f};
        int   o[4] = {0, 0, 0, 0};
        if (p < n) {
            const float cx = centers[p * 3 + 0];
            const float cy = centers[p * 3 + 1];
            const float cz = centers[p * 3 + 2];
            const int   b  = bidx[p];
            const float* tr = Tr + b * 16;
            const float c0 = tr[0]*cx + tr[1]*cy + tr[2]*cz + tr[3];
            const float c1 = tr[4]*cx + tr[5]*cy + tr[6]*cz + tr[7];
            const float c2 = tr[8]*cx + tr[9]*cy + tr[10]*cz + tr[11];
            const float c3 = tr[12]*cx + tr[13]*cy + tr[14]*cz + tr[15];
            const float* r0 = R0 + b * 16;
            const float e0 = r0[0]*c0 + r0[1]*c1 + r0[2]*c2 + r0[3]*c3;
            const float e1 = r0[4]*c0 + r0[5]*c1 + r0[6]*c2 + r0[7]*c3;
            const float e2 = r0[8]*c0 + r0[9]*c1 + r0[10]*c2 + r0[11]*c3;
            const float e3 = r0[12]*c0 + r0[13]*c1 + r0[14]*c2 + r0[15]*c3;
            const float* p2 = P2 + b * 12;
            const float ix = p2[0]*e0 + p2[1]*e1 + p2[2]*e2  + p2[3]*e3;
            const float iy = p2[4]*e0 + p2[5]*e1 + p2[6]*e2  + p2[7]*e3;
            const float iz = p2[8]*e0 + p2[9]*e1 + p2[10]*e2 + p2[11]*e3;
            const float depth = fmaxf(iz, 1e-5f);
            const float u = ix / depth;
            const float v = iy / depth;
            const bool valid = (iz > 0.f) && (u >= 0.f) && (u < (float)IMG_W)
                                         && (v >= 0.f) && (v < (float)IMG_H);
            const float x0f = floorf(u), y0f = floorf(v);
            const float wx1 = u - x0f, wx0 = 1.f - wx1;
            const float wy1 = v - y0f, wy0 = 1.f - wy1;
            const float cwv[4] = {wx0 * wy0, wx1 * wy0, wx0 * wy1, wx1 * wy1};
            #pragma unroll
            for (int j = 0; j < 4; ++j) {
                const float xf = x0f + (float)(j & 1);
                const float yf = y0f + (float)(j >> 1);
                const bool inb = (xf >= 0.f) && (xf <= (float)(IMG_W - 1))
                              && (yf >= 0.f) && (yf <= (float)(IMG_H - 1));
                const int xc = (int)fminf(fmaxf(xf, 0.f), (float)(IMG_W - 1));
                const int yc = (int)fminf(fmaxf(yf, 0.f), (float)(IMG_H - 1));
                w[j] = (valid && inb) ? cwv[j] : 0.f;
                o[j] = b * C_IMG * HWPIX + yc * IMG_W + xc;
            }
        }
        #pragma unroll
        for (int j = 0; j < 4; ++j) { sWg[tid][j] = w[j]; sOf[tid][j] = o[j]; }
    }

    f32x4 acc[4][4];
    #pragma unroll
    for (int i = 0; i < 4; ++i)
        #pragma unroll
        for (int j = 0; j < 4; ++j)
            acc[i][j] = (f32x4){0.f, 0.f, 0.f, 0.f};

    const int lane = tid & 63;
    const int wid  = tid >> 6;
    const int l15  = lane & 15;
    const int quad = lane >> 4;
    const int sp   = tid >> 2;
    const int ssub = tid & 3;

    __syncthreads();

    for (int ck = 0; ck < C_IMG / BK; ++ck) {
        {
            const float cw0 = sWg[sp][0], cw1 = sWg[sp][1], cw2 = sWg[sp][2], cw3 = sWg[sp][3];
            const int   co0 = sOf[sp][0], co1 = sOf[sp][1], co2 = sOf[sp][2], co3 = sOf[sp][3];
            const int   cb  = ck * BK + ssub * 16;
            const float* ib = img;
            #pragma unroll
            for (int h = 0; h < 2; ++h) {
                uint4 ov;
                unsigned* op = (unsigned*)&ov;
                #pragma unroll
                for (int wI = 0; wI < 4; ++wI) {
                    const int c = cb + h * 8 + 2 * wI;
                    const float vlo = cw0*ib[co0 + c*HWPIX] + cw1*ib[co1 + c*HWPIX]
                                    + cw2*ib[co2 + c*HWPIX] + cw3*ib[co3 + c*HWPIX];
                    const float vhi = cw0*ib[co0 + (c+1)*HWPIX] + cw1*ib[co1 + (c+1)*HWPIX]
                                    + cw2*ib[co2 + (c+1)*HWPIX] + cw3*ib[co3 + (c+1)*HWPIX];
                    op[wI] = pack2(vlo, vhi);
                }
                *(uint4*)&sS[sp][ssub * 16 + h * 8] = ov;
            }
        }
        {
            #pragma unroll
            for (int pass = 0; pass < 4; ++pass) {
                const int r = pass * 64 + (tid >> 2);
                const int c = (tid & 3) * 16;
                const float* wr = alw + (size_t)r * C_IMG + ck * BK + c;
                const float4 f0 = *(const float4*)(wr + 0);
                const float4 f1 = *(const float4*)(wr + 4);
                const float4 f2 = *(const float4*)(wr + 8);
                const float4 f3 = *(const float4*)(wr + 12);
                uint4 oa, ob;
                oa.x = pack2(f0.x, f0.y); oa.y = pack2(f0.z, f0.w);
                oa.z = pack2(f1.x, f1.y); oa.w = pack2(f1.z, f1.w);
                ob.x = pack2(f2.x, f2.y); ob.y = pack2(f2.z, f2.w);
                ob.z = pack2(f3.x, f3.y); ob.w = pack2(f3.z, f3.w);
                *(uint4*)&sW[r][c]     = oa;
                *(uint4*)&sW[r][c + 8] = ob;
            }
        }
        __syncthreads();

        #pragma unroll
        for (int kk = 0; kk < 2; ++kk) {
            bf16x8 af[4], bfr[4];
            #pragma unroll
            for (int mt = 0; mt < 4; ++mt)
                af[mt] = *(const bf16x8*)&sS[mt * 16 + l15][kk * 32 + quad * 8];
            #pragma unroll
            for (int nt = 0; nt < 4; ++nt)
                bfr[nt] = *(const bf16x8*)&sW[wid * 64 + nt * 16 + l15][kk * 32 + quad * 8];
            #pragma unroll
            for (int mt = 0; mt < 4; ++mt)
                #pragma unroll
                for (int nt = 0; nt < 4; ++nt)
                    acc[mt][nt] = __builtin_amdgcn_mfma_f32_16x16x32_bf16(
                        af[mt], bfr[nt], acc[mt][nt], 0, 0, 0);
        }
        __syncthreads();
    }

    #pragma unroll
    for (int mt = 0; mt < 4; ++mt) {
        #pragma unroll
        for (int r = 0; r < 4; ++r) {
            const int p = pt0 + mt * 16 + quad * 4 + r;
            if (p < n) {
                #pragma unroll
                for (int nt = 0; nt < 4; ++nt) {
                    const int nc = wid * 64 + nt * 16 + l15;
                    const size_t idx = (size_t)p * C_PT + nc;
                    out[idx] = pf[idx] + alb[nc] + acc[mt][nt][r];
                }
            }
        }
    }
}

extern "C" void kernel_launch(void* const* d_in, const int* in_sizes, int n_in,
                              void* d_out, int out_size, void* d_ws, size_t ws_size,
                              hipStream_t stream) {
    const float* pf      = (const float*)d_in[0];
    const float* centers = (const float*)d_in[1];
    const float* img     = (const float*)d_in[2];
    const float* P2      = (const float*)d_in[3];
    const float* R0      = (const float*)d_in[4];
    const float* Tr      = (const float*)d_in[5];
    const float* alw     = (const float*)d_in[6];
    const float* alb     = (const float*)d_in[7];
    const int*   bidx    = (const int*)d_in[8];
    float*       out     = (float*)d_out;

    const int n  = in_sizes[8];           // 100000 points
    const int bs = in_sizes[3] / 12;      // P2 is (BS,3,4)
    const int nblk = (n + MP - 1) / MP;

    const size_t timg = (size_t)bs * HWPIX * C_IMG * sizeof(unsigned short);
    const size_t tw   = (size_t)C_PT * C_IMG * sizeof(unsigned short);
    if (ws_size >= timg + tw) {
        unsigned short* imgT = (unsigned short*)d_ws;
        unsigned short* alwT = (unsigned short*)((char*)d_ws + timg);
        transpose_kernel<<<dim3(HWPIX / 32, C_IMG / 64, bs), dim3(32, 8), 0, stream>>>(img, imgT);
        cvt_w_kernel<<<dim3((C_PT * C_IMG / 8) / 256), 256, 0, stream>>>(alw, alwT);
        fused_trans_kernel<<<nblk, 256, 0, stream>>>(
            pf, centers, imgT, alwT, P2, R0, Tr, alb, bidx, out, n);
    } else {
        fused_fallback_kernel<<<nblk, 256, 0, stream>>>(
            pf, centers, img, P2, R0, Tr, alw, alb, bidx, out, n);
    }
}

// Round 2
// 386.476 us; speedup vs baseline: 1.0565x; 1.0254x over previous
//
#include <hip/hip_runtime.h>

#define C_IMG 512
#define C_PT  256
#define IMG_H 48
#define IMG_W 160
#define HWPIX (IMG_H * IMG_W)

#define MP   64     // points per block (fallback path)
#define BK   64
#define SPAD 72

typedef short bf16x8 __attribute__((ext_vector_type(8)));
typedef float f32x4  __attribute__((ext_vector_type(4)));

static __device__ __forceinline__ unsigned short f2bf(float f) {
    unsigned u = __float_as_uint(f);
    u += 0x7fffu + ((u >> 16) & 1u);   // RNE
    return (unsigned short)(u >> 16);
}
static __device__ __forceinline__ unsigned pack2(float lo, float hi) {
    return (unsigned)f2bf(lo) | ((unsigned)f2bf(hi) << 16);
}
static __device__ __forceinline__ float bflo(unsigned v) { return __uint_as_float(v << 16); }
static __device__ __forceinline__ float bfhi(unsigned v) { return __uint_as_float(v & 0xffff0000u); }

// ---------------- align_w f32 [C_PT][C_IMG] -> bf16 same layout ----------------
__global__ __launch_bounds__(256)
void cvt_w_kernel(const float* __restrict__ alw, unsigned short* __restrict__ alwT) {
    const int i = (blockIdx.x * 256 + threadIdx.x) * 8;
    const float4 a = *(const float4*)(alw + i);
    const float4 b = *(const float4*)(alw + i + 4);
    uint4 o;
    o.x = pack2(a.x, a.y); o.y = pack2(a.z, a.w);
    o.z = pack2(b.x, b.y); o.w = pack2(b.z, b.w);
    *(uint4*)(alwT + i) = o;
}

// ---------------- per-pixel projection GEMM ----------------
// PT[b][hw][c_pt] = sum_c img[b][c][hw] * W[c_pt][c]   (bf16 out, f32 acc)
// Block: 64 pixels x 256 c_pt, 4 waves (wave = 64 c_pt). No LDS: A-frags are
// per-lane direct f32 loads (lanes sweep contiguous pixels -> 64B segments;
// the 4 waves read identical A addresses -> L1 broadcast). B-frags are
// per-lane contiguous bf16x8 from the pre-converted W (L2-resident).
__global__ __launch_bounds__(256)
void proj_kernel(const float* __restrict__ img,
                 const unsigned short* __restrict__ wbf,
                 unsigned short* __restrict__ PT) {
    const int blk  = blockIdx.x;
    const int b    = blk / (HWPIX / 64);
    const int hw0  = (blk % (HWPIX / 64)) * 64;
    const int tid  = threadIdx.x;
    const int lane = tid & 63;
    const int wid  = tid >> 6;
    const int l15  = lane & 15;
    const int quad = lane >> 4;

    f32x4 acc[4][4];
    #pragma unroll
    for (int i = 0; i < 4; ++i)
        #pragma unroll
        for (int j = 0; j < 4; ++j)
            acc[i][j] = (f32x4){0.f, 0.f, 0.f, 0.f};

    // per-lane bases
    const float* aim = img + (size_t)b * C_IMG * HWPIX + hw0 + l15;      // + c*HWPIX + mt*16
    const unsigned short* bw = wbf + (size_t)(wid * 64 + l15) * C_IMG + quad * 8;

    for (int ck = 0; ck < C_IMG / 64; ++ck) {
        #pragma unroll
        for (int kk = 0; kk < 2; ++kk) {
            const int c0 = ck * 64 + kk * 32 + quad * 8;   // this lane's first k
            bf16x8 af[4];
            #pragma unroll
            for (int mt = 0; mt < 4; ++mt) {
                const float* ap = aim + (size_t)c0 * HWPIX + mt * 16;
                float f[8];
                #pragma unroll
                for (int j = 0; j < 8; ++j) f[j] = ap[j * HWPIX];
                union { unsigned u[4]; bf16x8 v; } cv;
                cv.u[0] = pack2(f[0], f[1]);
                cv.u[1] = pack2(f[2], f[3]);
                cv.u[2] = pack2(f[4], f[5]);
                cv.u[3] = pack2(f[6], f[7]);
                af[mt] = cv.v;
            }
            bf16x8 bfr[4];
            #pragma unroll
            for (int nt = 0; nt < 4; ++nt)
                bfr[nt] = *(const bf16x8*)(bw + (size_t)(nt * 16) * C_IMG + ck * 64 + kk * 32);
            #pragma unroll
            for (int mt = 0; mt < 4; ++mt)
                #pragma unroll
                for (int nt = 0; nt < 4; ++nt)
                    acc[mt][nt] = __builtin_amdgcn_mfma_f32_16x16x32_bf16(
                        af[mt], bfr[nt], acc[mt][nt], 0, 0, 0);
        }
    }

    // epilogue: C/D layout col = l15 (c_pt), row = quad*4 + r (pixel)
    #pragma unroll
    for (int mt = 0; mt < 4; ++mt) {
        #pragma unroll
        for (int r = 0; r < 4; ++r) {
            const int pix = mt * 16 + quad * 4 + r;
            unsigned short* dst = PT + (size_t)(b * HWPIX + hw0 + pix) * C_PT;
            #pragma unroll
            for (int nt = 0; nt < 4; ++nt) {
                const int nc = wid * 64 + nt * 16 + l15;
                dst[nc] = f2bf(acc[mt][nt][r]);
            }
        }
    }
}

// ---------------- per-point bilinear interp in projected (C_PT) space ----------------
// out[p][c] = pf[p][c] + alb[c] + sum_j w_j * PT[corner_j][c]
// One point per wave-iteration; lane handles 4 channels. No LDS, no barriers.
#define PPW 4
__global__ __launch_bounds__(256)
void point_kernel(const float* __restrict__ pf,
                  const float* __restrict__ centers,
                  const unsigned short* __restrict__ PT,
                  const float* __restrict__ P2,
                  const float* __restrict__ R0,
                  const float* __restrict__ Tr,
                  const float* __restrict__ alb,
                  const int*   __restrict__ bidx,
                  float* __restrict__ out,
                  int n)
{
    const int tid  = threadIdx.x;
    const int lane = tid & 63;
    const int wid  = tid >> 6;
    const int p0   = blockIdx.x * (4 * PPW) + wid * PPW;

    const float4 ab = *(const float4*)(alb + lane * 4);

    #pragma unroll
    for (int it = 0; it < PPW; ++it) {
        const int p = p0 + it;
        if (p >= n) break;

        // projection — computed redundantly in all lanes (wave-uniform)
        const float cx = centers[p * 3 + 0];
        const float cy = centers[p * 3 + 1];
        const float cz = centers[p * 3 + 2];
        const int   b  = bidx[p];
        const float* tr = Tr + b * 16;
        const float c0 = tr[0]*cx + tr[1]*cy + tr[2]*cz + tr[3];
        const float c1 = tr[4]*cx + tr[5]*cy + tr[6]*cz + tr[7];
        const float c2 = tr[8]*cx + tr[9]*cy + tr[10]*cz + tr[11];
        const float c3 = tr[12]*cx + tr[13]*cy + tr[14]*cz + tr[15];
        const float* r0 = R0 + b * 16;
        const float e0 = r0[0]*c0 + r0[1]*c1 + r0[2]*c2 + r0[3]*c3;
        const float e1 = r0[4]*c0 + r0[5]*c1 + r0[6]*c2 + r0[7]*c3;
        const float e2 = r0[8]*c0 + r0[9]*c1 + r0[10]*c2 + r0[11]*c3;
        const float e3 = r0[12]*c0 + r0[13]*c1 + r0[14]*c2 + r0[15]*c3;
        const float* p2 = P2 + b * 12;
        const float ix = p2[0]*e0 + p2[1]*e1 + p2[2]*e2  + p2[3]*e3;
        const float iy = p2[4]*e0 + p2[5]*e1 + p2[6]*e2  + p2[7]*e3;
        const float iz = p2[8]*e0 + p2[9]*e1 + p2[10]*e2 + p2[11]*e3;
        const float depth = fmaxf(iz, 1e-5f);
        const float u = ix / depth;
        const float v = iy / depth;
        const bool valid = (iz > 0.f) && (u >= 0.f) && (u < (float)IMG_W)
                                     && (v >= 0.f) && (v < (float)IMG_H);
        const float x0f = floorf(u), y0f = floorf(v);
        const float wx1 = u - x0f, wx0 = 1.f - wx1;
        const float wy1 = v - y0f, wy0 = 1.f - wy1;
        const float cwv[4] = {wx0 * wy0, wx1 * wy0, wx0 * wy1, wx1 * wy1};
        float wgt[4]; int off[4];
        #pragma unroll
        for (int j = 0; j < 4; ++j) {
            const float xf = x0f + (float)(j & 1);
            const float yf = y0f + (float)(j >> 1);
            const bool inb = (xf >= 0.f) && (xf <= (float)(IMG_W - 1))
                          && (yf >= 0.f) && (yf <= (float)(IMG_H - 1));
            const int xc = (int)fminf(fmaxf(xf, 0.f), (float)(IMG_W - 1));
            const int yc = (int)fminf(fmaxf(yf, 0.f), (float)(IMG_H - 1));
            wgt[j] = (valid && inb) ? cwv[j] : 0.f;
            off[j] = ((b * IMG_H + yc) * IMG_W + xc) * C_PT;
        }

        float s0 = 0.f, s1 = 0.f, s2 = 0.f, s3 = 0.f;
        #pragma unroll
        for (int j = 0; j < 4; ++j) {
            const uint2 g = *(const uint2*)(PT + off[j] + lane * 4);
            s0 = fmaf(wgt[j], bflo(g.x), s0);
            s1 = fmaf(wgt[j], bfhi(g.x), s1);
            s2 = fmaf(wgt[j], bflo(g.y), s2);
            s3 = fmaf(wgt[j], bfhi(g.y), s3);
        }

        const size_t idx = (size_t)p * C_PT + lane * 4;
        const float4 pv = *(const float4*)(pf + idx);
        float4 ov;
        ov.x = pv.x + ab.x + s0;
        ov.y = pv.y + ab.y + s1;
        ov.z = pv.z + ab.z + s2;
        ov.w = pv.w + ab.w + s3;
        *(float4*)(out + idx) = ov;
    }
}

// ---------------- fallback: monolithic single-kernel path (no workspace) ----------------
__global__ __launch_bounds__(256)
void fused_fallback_kernel(const float* __restrict__ pf,
                           const float* __restrict__ centers,
                           const float* __restrict__ img,
                           const float* __restrict__ P2,
                           const float* __restrict__ R0,
                           const float* __restrict__ Tr,
                           const float* __restrict__ alw,
                           const float* __restrict__ alb,
                           const int*   __restrict__ bidx,
                           float* __restrict__ out,
                           int n)
{
    __shared__ float          sWg[MP][4];
    __shared__ int            sOf[MP][4];
    __shared__ unsigned short sS[MP][SPAD];
    __shared__ unsigned short sW[C_PT][SPAD];

    const int tid = threadIdx.x;
    const int pt0 = blockIdx.x * MP;

    if (tid < MP) {
        const int p = pt0 + tid;
        float w[4] = {0.f, 0.f, 0.f, 0.f};
        int   o[4] = {0, 0, 0, 0};
        if (p < n) {
            const float cx = centers[p * 3 + 0];
            const float cy = centers[p * 3 + 1];
            const float cz = centers[p * 3 + 2];
            const int   b  = bidx[p];
            const float* tr = Tr + b * 16;
            const float c0 = tr[0]*cx + tr[1]*cy + tr[2]*cz + tr[3];
            const float c1 = tr[4]*cx + tr[5]*cy + tr[6]*cz + tr[7];
            const float c2 = tr[8]*cx + tr[9]*cy + tr[10]*cz + tr[11];
            const float c3 = tr[12]*cx + tr[13]*cy + tr[14]*cz + tr[15];
            const float* r0 = R0 + b * 16;
            const float e0 = r0[0]*c0 + r0[1]*c1 + r0[2]*c2 + r0[3]*c3;
            const float e1 = r0[4]*c0 + r0[5]*c1 + r0[6]*c2 + r0[7]*c3;
            const float e2 = r0[8]*c0 + r0[9]*c1 + r0[10]*c2 + r0[11]*c3;
            const float e3 = r0[12]*c0 + r0[13]*c1 + r0[14]*c2 + r0[15]*c3;
            const float* p2 = P2 + b * 12;
            const float ix = p2[0]*e0 + p2[1]*e1 + p2[2]*e2  + p2[3]*e3;
            const float iy = p2[4]*e0 + p2[5]*e1 + p2[6]*e2  + p2[7]*e3;
            const float iz = p2[8]*e0 + p2[9]*e1 + p2[10]*e2 + p2[11]*e3;
            const float depth = fmaxf(iz, 1e-5f);
            const float u = ix / depth;
            const float v = iy / depth;
            const bool valid = (iz > 0.f) && (u >= 0.f) && (u < (float)IMG_W)
                                         && (v >= 0.f) && (v < (float)IMG_H);
            const float x0f = floorf(u), y0f = floorf(v);
            const float wx1 = u - x0f, wx0 = 1.f - wx1;
            const float wy1 = v - y0f, wy0 = 1.f - wy1;
            const float cwv[4] = {wx0 * wy0, wx1 * wy0, wx0 * wy1, wx1 * wy1};
            #pragma unroll
            for (int j = 0; j < 4; ++j) {
                const float xf = x0f + (float)(j & 1);
                const float yf = y0f + (float)(j >> 1);
                const bool inb = (xf >= 0.f) && (xf <= (float)(IMG_W - 1))
                              && (yf >= 0.f) && (yf <= (float)(IMG_H - 1));
                const int xc = (int)fminf(fmaxf(xf, 0.f), (float)(IMG_W - 1));
                const int yc = (int)fminf(fmaxf(yf, 0.f), (float)(IMG_H - 1));
                w[j] = (valid && inb) ? cwv[j] : 0.f;
                o[j] = b * C_IMG * HWPIX + yc * IMG_W + xc;
            }
        }
        #pragma unroll
        for (int j = 0; j < 4; ++j) { sWg[tid][j] = w[j]; sOf[tid][j] = o[j]; }
    }

    f32x4 acc[4][4];
    #pragma unroll
    for (int i = 0; i < 4; ++i)
        #pragma unroll
        for (int j = 0; j < 4; ++j)
            acc[i][j] = (f32x4){0.f, 0.f, 0.f, 0.f};

    const int lane = tid & 63;
    const int wid  = tid >> 6;
    const int l15  = lane & 15;
    const int quad = lane >> 4;
    const int sp   = tid >> 2;
    const int ssub = tid & 3;

    __syncthreads();

    for (int ck = 0; ck < C_IMG / BK; ++ck) {
        {
            const float cw0 = sWg[sp][0], cw1 = sWg[sp][1], cw2 = sWg[sp][2], cw3 = sWg[sp][3];
            const int   co0 = sOf[sp][0], co1 = sOf[sp][1], co2 = sOf[sp][2], co3 = sOf[sp][3];
            const int   cb  = ck * BK + ssub * 16;
            const float* ib = img;
            #pragma unroll
            for (int h = 0; h < 2; ++h) {
                uint4 ov;
                unsigned* op = (unsigned*)&ov;
                #pragma unroll
                for (int wI = 0; wI < 4; ++wI) {
                    const int c = cb + h * 8 + 2 * wI;
                    const float vlo = cw0*ib[co0 + c*HWPIX] + cw1*ib[co1 + c*HWPIX]
                                    + cw2*ib[co2 + c*HWPIX] + cw3*ib[co3 + c*HWPIX];
                    const float vhi = cw0*ib[co0 + (c+1)*HWPIX] + cw1*ib[co1 + (c+1)*HWPIX]
                                    + cw2*ib[co2 + (c+1)*HWPIX] + cw3*ib[co3 + (c+1)*HWPIX];
                    op[wI] = pack2(vlo, vhi);
                }
                *(uint4*)&sS[sp][ssub * 16 + h * 8] = ov;
            }
        }
        {
            #pragma unroll
            for (int pass = 0; pass < 4; ++pass) {
                const int r = pass * 64 + (tid >> 2);
                const int c = (tid & 3) * 16;
                const float* wr = alw + (size_t)r * C_IMG + ck * BK + c;
                const float4 f0 = *(const float4*)(wr + 0);
                const float4 f1 = *(const float4*)(wr + 4);
                const float4 f2 = *(const float4*)(wr + 8);
                const float4 f3 = *(const float4*)(wr + 12);
                uint4 oa, ob;
                oa.x = pack2(f0.x, f0.y); oa.y = pack2(f0.z, f0.w);
                oa.z = pack2(f1.x, f1.y); oa.w = pack2(f1.z, f1.w);
                ob.x = pack2(f2.x, f2.y); ob.y = pack2(f2.z, f2.w);
                ob.z = pack2(f3.x, f3.y); ob.w = pack2(f3.z, f3.w);
                *(uint4*)&sW[r][c]     = oa;
                *(uint4*)&sW[r][c + 8] = ob;
            }
        }
        __syncthreads();

        #pragma unroll
        for (int kk = 0; kk < 2; ++kk) {
            bf16x8 af[4], bfr[4];
            #pragma unroll
            for (int mt = 0; mt < 4; ++mt)
                af[mt] = *(const bf16x8*)&sS[mt * 16 + l15][kk * 32 + quad * 8];
            #pragma unroll
            for (int nt = 0; nt < 4; ++nt)
                bfr[nt] = *(const bf16x8*)&sW[wid * 64 + nt * 16 + l15][kk * 32 + quad * 8];
            #pragma unroll
            for (int mt = 0; mt < 4; ++mt)
                #pragma unroll
                for (int nt = 0; nt < 4; ++nt)
                    acc[mt][nt] = __builtin_amdgcn_mfma_f32_16x16x32_bf16(
                        af[mt], bfr[nt], acc[mt][nt], 0, 0, 0);
        }
        __syncthreads();
    }

    #pragma unroll
    for (int mt = 0; mt < 4; ++mt) {
        #pragma unroll
        for (int r = 0; r < 4; ++r) {
            const int p = pt0 + mt * 16 + quad * 4 + r;
            if (p < n) {
                #pragma unroll
                for (int nt = 0; nt < 4; ++nt) {
                    const int nc = wid * 64 + nt * 16 + l15;
                    const size_t idx = (size_t)p * C_PT + nc;
                    out[idx] = pf[idx] + alb[nc] + acc[mt][nt][r];
                }
            }
        }
    }
}

extern "C" void kernel_launch(void* const* d_in, const int* in_sizes, int n_in,
                              void* d_out, int out_size, void* d_ws, size_t ws_size,
                              hipStream_t stream) {
    const float* pf      = (const float*)d_in[0];
    const float* centers = (const float*)d_in[1];
    const float* img     = (const float*)d_in[2];
    const float* P2      = (const float*)d_in[3];
    const float* R0      = (const float*)d_in[4];
    const float* Tr      = (const float*)d_in[5];
    const float* alw     = (const float*)d_in[6];
    const float* alb     = (const float*)d_in[7];
    const int*   bidx    = (const int*)d_in[8];
    float*       out     = (float*)d_out;

    const int n  = in_sizes[8];           // 100000 points
    const int bs = in_sizes[3] / 12;      // P2 is (BS,3,4)

    const size_t tpt = (size_t)bs * HWPIX * C_PT * sizeof(unsigned short);
    const size_t tw  = (size_t)C_PT * C_IMG * sizeof(unsigned short);
    if (ws_size >= tpt + tw) {
        unsigned short* PT  = (unsigned short*)d_ws;
        unsigned short* wbf = (unsigned short*)((char*)d_ws + tpt);
        cvt_w_kernel<<<(C_PT * C_IMG / 8) / 256, 256, 0, stream>>>(alw, wbf);
        proj_kernel<<<bs * (HWPIX / 64), 256, 0, stream>>>(img, wbf, PT);
        point_kernel<<<(n + 4 * PPW * 4 - 1) / (4 * PPW * 4) * 4, 256, 0, stream>>>(
            pf, centers, PT, P2, R0, Tr, alb, bidx, out, n);
    } else {
        const int nblk = (n + MP - 1) / MP;
        fused_fallback_kernel<<<nblk, 256, 0, stream>>>(
            pf, centers, img, P2, R0, Tr, alw, alb, bidx, out, n);
    }
}

// Round 3
// 334.780 us; speedup vs baseline: 1.2196x; 1.1544x over previous
//
#include <hip/hip_runtime.h>

#define C_IMG 512
#define C_PT  256
#define IMG_H 48
#define IMG_W 160
#define HWPIX (IMG_H * IMG_W)

#define MP   64     // fallback path tile
#define BK   64
#define SPAD 72

typedef short bf16x8 __attribute__((ext_vector_type(8)));
typedef float f32x4  __attribute__((ext_vector_type(4)));
typedef unsigned u32x4 __attribute__((ext_vector_type(4)));

static __device__ __forceinline__ unsigned short f2bf(float f) {
    unsigned u = __float_as_uint(f);
    u += 0x7fffu + ((u >> 16) & 1u);   // RNE
    return (unsigned short)(u >> 16);
}
static __device__ __forceinline__ unsigned pack2(float lo, float hi) {
    return (unsigned)f2bf(lo) | ((unsigned)f2bf(hi) << 16);
}
// round-half-up variants (2 ops instead of 4; same error bound as RNE)
static __device__ __forceinline__ unsigned short f2bf_hu(float f) {
    return (unsigned short)((__float_as_uint(f) + 0x8000u) >> 16);
}
static __device__ __forceinline__ unsigned pack2_hu(float lo, float hi) {
    return ((__float_as_uint(lo) + 0x8000u) >> 16)
         | ((__float_as_uint(hi) + 0x8000u) & 0xffff0000u);
}
static __device__ __forceinline__ float bflo(unsigned v) { return __uint_as_float(v << 16); }
static __device__ __forceinline__ float bfhi(unsigned v) { return __uint_as_float(v & 0xffff0000u); }

// ---------------- align_w f32 [C_PT][C_IMG] -> bf16 same layout ----------------
__global__ __launch_bounds__(256)
void cvt_w_kernel(const float* __restrict__ alw, unsigned short* __restrict__ alwT) {
    const int i = (blockIdx.x * 256 + threadIdx.x) * 8;
    const float4 a = *(const float4*)(alw + i);
    const float4 b = *(const float4*)(alw + i + 4);
    uint4 o;
    o.x = pack2(a.x, a.y); o.y = pack2(a.z, a.w);
    o.z = pack2(b.x, b.y); o.w = pack2(b.z, b.w);
    *(uint4*)(alwT + i) = o;
}

// ---------------- per-point projection params (1 thread per point) ----------------
__global__ __launch_bounds__(256)
void params_kernel(const float* __restrict__ centers,
                   const float* __restrict__ P2,
                   const float* __restrict__ R0,
                   const float* __restrict__ Tr,
                   const int*   __restrict__ bidx,
                   u32x4* __restrict__ poff,
                   f32x4* __restrict__ pwgt,
                   int n)
{
    const int p = blockIdx.x * 256 + threadIdx.x;
    if (p >= n) return;
    const float cx = centers[p * 3 + 0];
    const float cy = centers[p * 3 + 1];
    const float cz = centers[p * 3 + 2];
    const int   b  = bidx[p];
    const float* tr = Tr + b * 16;
    const float c0 = tr[0]*cx + tr[1]*cy + tr[2]*cz + tr[3];
    const float c1 = tr[4]*cx + tr[5]*cy + tr[6]*cz + tr[7];
    const float c2 = tr[8]*cx + tr[9]*cy + tr[10]*cz + tr[11];
    const float c3 = tr[12]*cx + tr[13]*cy + tr[14]*cz + tr[15];
    const float* r0 = R0 + b * 16;
    const float e0 = r0[0]*c0 + r0[1]*c1 + r0[2]*c2 + r0[3]*c3;
    const float e1 = r0[4]*c0 + r0[5]*c1 + r0[6]*c2 + r0[7]*c3;
    const float e2 = r0[8]*c0 + r0[9]*c1 + r0[10]*c2 + r0[11]*c3;
    const float e3 = r0[12]*c0 + r0[13]*c1 + r0[14]*c2 + r0[15]*c3;
    const float* p2 = P2 + b * 12;
    const float ix = p2[0]*e0 + p2[1]*e1 + p2[2]*e2  + p2[3]*e3;
    const float iy = p2[4]*e0 + p2[5]*e1 + p2[6]*e2  + p2[7]*e3;
    const float iz = p2[8]*e0 + p2[9]*e1 + p2[10]*e2 + p2[11]*e3;
    const float depth = fmaxf(iz, 1e-5f);
    const float u = ix / depth;
    const float v = iy / depth;
    const bool valid = (iz > 0.f) && (u >= 0.f) && (u < (float)IMG_W)
                                 && (v >= 0.f) && (v < (float)IMG_H);
    const float x0f = floorf(u), y0f = floorf(v);
    const float wx1 = u - x0f, wx0 = 1.f - wx1;
    const float wy1 = v - y0f, wy0 = 1.f - wy1;
    const float cwv[4] = {wx0 * wy0, wx1 * wy0, wx0 * wy1, wx1 * wy1};
    f32x4 wg; u32x4 of;
    #pragma unroll
    for (int j = 0; j < 4; ++j) {
        const float xf = x0f + (float)(j & 1);
        const float yf = y0f + (float)(j >> 1);
        const bool inb = (xf >= 0.f) && (xf <= (float)(IMG_W - 1))
                      && (yf >= 0.f) && (yf <= (float)(IMG_H - 1));
        const int xc = (int)fminf(fmaxf(xf, 0.f), (float)(IMG_W - 1));
        const int yc = (int)fminf(fmaxf(yf, 0.f), (float)(IMG_H - 1));
        wg[j] = (valid && inb) ? cwv[j] : 0.f;
        of[j] = (unsigned)(((b * IMG_H + yc) * IMG_W + xc) * C_PT);
    }
    poff[p] = of;
    pwgt[p] = wg;
}

// ---------------- per-pixel projection GEMM (LDS-transposed A) ----------------
// PT[b][hw][c_pt] = sum_c img[b][c][hw] * W[c_pt][c]   (bf16 out, f32 acc)
// Block: 64 px x 256 c_pt, 4 waves. A-tile staged 64ch x 64px f32 in LDS via
// coalesced float4 loads (img native channel-major), double-buffered with
// issue-early/commit-late; strided column reads de-conflicted by a 16-px
// chunk XOR swizzle (chunk ^= (ch>>3)&3) -> 2-way max (free).
__global__ __launch_bounds__(256)
void proj_kernel(const float* __restrict__ img,
                 const unsigned short* __restrict__ wbf,
                 unsigned short* __restrict__ PT)
{
    __shared__ float sF[2][64][68];
    const int blk  = blockIdx.x;
    const int b    = blk / (HWPIX / 64);
    const int hw0  = (blk % (HWPIX / 64)) * 64;
    const int tid  = threadIdx.x;
    const int lane = tid & 63;
    const int wid  = tid >> 6;
    const int l15  = lane & 15;
    const int quad = lane >> 4;

    // staging: thread t owns channel row sr, px chunk scc (16 px = 4 float4)
    const int sr   = tid >> 2;
    const int scc  = tid & 3;
    const int sdst = ((scc ^ ((sr >> 3) & 3)) << 4);   // swizzled px base in LDS
    const float* gsrc = img + (size_t)b * C_IMG * HWPIX + hw0 + scc * 16;

    f32x4 acc[4][4];
    #pragma unroll
    for (int i = 0; i < 4; ++i)
        #pragma unroll
        for (int j = 0; j < 4; ++j)
            acc[i][j] = (f32x4){0.f, 0.f, 0.f, 0.f};

    const unsigned short* bw = wbf + (size_t)(wid * 64 + l15) * C_IMG + quad * 8;

    float4 st[4];
    {   // prologue: stage ck=0 into buffer 0
        const float* gp = gsrc + (size_t)sr * HWPIX;
        #pragma unroll
        for (int k = 0; k < 4; ++k) st[k] = *(const float4*)(gp + 4 * k);
        #pragma unroll
        for (int k = 0; k < 4; ++k) *(float4*)&sF[0][sr][sdst + 4 * k] = st[k];
    }
    __syncthreads();

    for (int ck = 0; ck < C_IMG / 64; ++ck) {
        const int cur = ck & 1;
        if (ck < C_IMG / 64 - 1) {          // issue next tile's loads early
            const float* gp = gsrc + (size_t)((ck + 1) * 64 + sr) * HWPIX;
            #pragma unroll
            for (int k = 0; k < 4; ++k) st[k] = *(const float4*)(gp + 4 * k);
        }
        #pragma unroll
        for (int kk = 0; kk < 2; ++kk) {
            bf16x8 af[4], bfr[4];
            #pragma unroll
            for (int nt = 0; nt < 4; ++nt)
                bfr[nt] = *(const bf16x8*)(bw + (size_t)(nt * 16) * C_IMG + ck * 64 + kk * 32);
            const int rbase = kk * 32 + quad * 8;
            #pragma unroll
            for (int mt = 0; mt < 4; ++mt) {
                const int col = ((mt ^ quad) << 4) + l15;   // matches store swizzle
                float f[8];
                #pragma unroll
                for (int j = 0; j < 8; ++j) f[j] = sF[cur][rbase + j][col];
                union { unsigned u[4]; bf16x8 v; } cv;
                #pragma unroll
                for (int w2 = 0; w2 < 4; ++w2)
                    cv.u[w2] = pack2_hu(f[2 * w2], f[2 * w2 + 1]);
                af[mt] = cv.v;
            }
            #pragma unroll
            for (int mt = 0; mt < 4; ++mt)
                #pragma unroll
                for (int nt = 0; nt < 4; ++nt)
                    acc[mt][nt] = __builtin_amdgcn_mfma_f32_16x16x32_bf16(
                        af[mt], bfr[nt], acc[mt][nt], 0, 0, 0);
        }
        if (ck < C_IMG / 64 - 1) {          // commit late into the other buffer
            #pragma unroll
            for (int k = 0; k < 4; ++k) *(float4*)&sF[cur ^ 1][sr][sdst + 4 * k] = st[k];
        }
        __syncthreads();
    }

    // epilogue: C/D layout col = l15 (c_pt), row = quad*4 + r (pixel)
    #pragma unroll
    for (int mt = 0; mt < 4; ++mt) {
        #pragma unroll
        for (int r = 0; r < 4; ++r) {
            const int pix = mt * 16 + quad * 4 + r;
            unsigned short* dst = PT + (size_t)(b * HWPIX + hw0 + pix) * C_PT + wid * 64 + l15;
            #pragma unroll
            for (int nt = 0; nt < 4; ++nt)
                dst[nt * 16] = f2bf_hu(acc[mt][nt][r]);
        }
    }
}

// ---------------- per-point bilinear interp in projected (C_PT) space ----------------
// Half-wave (32 lanes) per point, 8 channels per lane (dwordx4 gathers).
// Nontemporal pf/out stream so PT stays L3-resident.
__global__ __launch_bounds__(256)
void point_kernel(const float* __restrict__ pf,
                  const unsigned short* __restrict__ PT,
                  const float* __restrict__ alb,
                  const u32x4* __restrict__ poff,
                  const f32x4* __restrict__ pwgt,
                  float* __restrict__ out,
                  int n)
{
    const int tid  = threadIdx.x;
    const int lane = tid & 63;
    const int wid  = tid >> 6;
    const int sub  = lane >> 5;          // which point of the pair
    const int ch0  = (lane & 31) * 8;    // 8 channels per lane
    const int base = blockIdx.x * 32 + wid * 8 + sub;

    const f32x4 ab0 = *(const f32x4*)(alb + ch0);
    const f32x4 ab1 = *(const f32x4*)(alb + ch0 + 4);

    #pragma unroll
    for (int it = 0; it < 4; ++it) {
        const int p = base + it * 2;
        if (p < n) {
            const u32x4 of = poff[p];
            const f32x4 wg = pwgt[p];
            float s0 = 0.f, s1 = 0.f, s2 = 0.f, s3 = 0.f;
            float s4 = 0.f, s5 = 0.f, s6 = 0.f, s7 = 0.f;
            #pragma unroll
            for (int j = 0; j < 4; ++j) {
                const u32x4 g = *(const u32x4*)(PT + of[j] + ch0);
                const float w = wg[j];
                s0 = fmaf(w, bflo(g[0]), s0); s1 = fmaf(w, bfhi(g[0]), s1);
                s2 = fmaf(w, bflo(g[1]), s2); s3 = fmaf(w, bfhi(g[1]), s3);
                s4 = fmaf(w, bflo(g[2]), s4); s5 = fmaf(w, bfhi(g[2]), s5);
                s6 = fmaf(w, bflo(g[3]), s6); s7 = fmaf(w, bfhi(g[3]), s7);
            }
            const size_t idx = (size_t)p * C_PT + ch0;
            const f32x4 a  = __builtin_nontemporal_load((const f32x4*)(pf + idx));
            const f32x4 b4 = __builtin_nontemporal_load((const f32x4*)(pf + idx + 4));
            f32x4 o0, o1;
            o0[0] = a[0] + ab0[0] + s0;  o0[1] = a[1] + ab0[1] + s1;
            o0[2] = a[2] + ab0[2] + s2;  o0[3] = a[3] + ab0[3] + s3;
            o1[0] = b4[0] + ab1[0] + s4; o1[1] = b4[1] + ab1[1] + s5;
            o1[2] = b4[2] + ab1[2] + s6; o1[3] = b4[3] + ab1[3] + s7;
            __builtin_nontemporal_store(o0, (f32x4*)(out + idx));
            __builtin_nontemporal_store(o1, (f32x4*)(out + idx + 4));
        }
    }
}

// ---------------- fallback: monolithic single-kernel path (no workspace) ----------------
__global__ __launch_bounds__(256)
void fused_fallback_kernel(const float* __restrict__ pf,
                           const float* __restrict__ centers,
                           const float* __restrict__ img,
                           const float* __restrict__ P2,
                           const float* __restrict__ R0,
                           const float* __restrict__ Tr,
                           const float* __restrict__ alw,
                           const float* __restrict__ alb,
                           const int*   __restrict__ bidx,
                           float* __restrict__ out,
                           int n)
{
    __shared__ float          sWg[MP][4];
    __shared__ int            sOf[MP][4];
    __shared__ unsigned short sS[MP][SPAD];
    __shared__ unsigned short sW[C_PT][SPAD];

    const int tid = threadIdx.x;
    const int pt0 = blockIdx.x * MP;

    if (tid < MP) {
        const int p = pt0 + tid;
        float w[4] = {0.f, 0.f, 0.f, 0.f};
        int   o[4] = {0, 0, 0, 0};
        if (p < n) {
            const float cx = centers[p * 3 + 0];
            const float cy = centers[p * 3 + 1];
            const float cz = centers[p * 3 + 2];
            const int   b  = bidx[p];
            const float* tr = Tr + b * 16;
            const float c0 = tr[0]*cx + tr[1]*cy + tr[2]*cz + tr[3];
            const float c1 = tr[4]*cx + tr[5]*cy + tr[6]*cz + tr[7];
            const float c2 = tr[8]*cx + tr[9]*cy + tr[10]*cz + tr[11];
            const float c3 = tr[12]*cx + tr[13]*cy + tr[14]*cz + tr[15];
            const float* r0 = R0 + b * 16;
            const float e0 = r0[0]*c0 + r0[1]*c1 + r0[2]*c2 + r0[3]*c3;
            const float e1 = r0[4]*c0 + r0[5]*c1 + r0[6]*c2 + r0[7]*c3;
            const float e2 = r0[8]*c0 + r0[9]*c1 + r0[10]*c2 + r0[11]*c3;
            const float e3 = r0[12]*c0 + r0[13]*c1 + r0[14]*c2 + r0[15]*c3;
            const float* p2 = P2 + b * 12;
            const float ix = p2[0]*e0 + p2[1]*e1 + p2[2]*e2  + p2[3]*e3;
            const float iy = p2[4]*e0 + p2[5]*e1 + p2[6]*e2  + p2[7]*e3;
            const float iz = p2[8]*e0 + p2[9]*e1 + p2[10]*e2 + p2[11]*e3;
            const float depth = fmaxf(iz, 1e-5f);
            const float u = ix / depth;
            const float v = iy / depth;
            const bool valid = (iz > 0.f) && (u >= 0.f) && (u < (float)IMG_W)
                                         && (v >= 0.f) && (v < (float)IMG_H);
            const float x0f = floorf(u), y0f = floorf(v);
            const float wx1 = u - x0f, wx0 = 1.f - wx1;
            const float wy1 = v - y0f, wy0 = 1.f - wy1;
            const float cwv[4] = {wx0 * wy0, wx1 * wy0, wx0 * wy1, wx1 * wy1};
            #pragma unroll
            for (int j = 0; j < 4; ++j) {
                const float xf = x0f + (float)(j & 1);
                const float yf = y0f + (float)(j >> 1);
                const bool inb = (xf >= 0.f) && (xf <= (float)(IMG_W - 1))
                              && (yf >= 0.f) && (yf <= (float)(IMG_H - 1));
                const int xc = (int)fminf(fmaxf(xf, 0.f), (float)(IMG_W - 1));
                const int yc = (int)fminf(fmaxf(yf, 0.f), (float)(IMG_H - 1));
                w[j] = (valid && inb) ? cwv[j] : 0.f;
                o[j] = b * C_IMG * HWPIX + yc * IMG_W + xc;
            }
        }
        #pragma unroll
        for (int j = 0; j < 4; ++j) { sWg[tid][j] = w[j]; sOf[tid][j] = o[j]; }
    }

    f32x4 acc[4][4];
    #pragma unroll
    for (int i = 0; i < 4; ++i)
        #pragma unroll
        for (int j = 0; j < 4; ++j)
            acc[i][j] = (f32x4){0.f, 0.f, 0.f, 0.f};

    const int lane = tid & 63;
    const int wid  = tid >> 6;
    const int l15  = lane & 15;
    const int quad = lane >> 4;
    const int sp   = tid >> 2;
    const int ssub = tid & 3;

    __syncthreads();

    for (int ck = 0; ck < C_IMG / BK; ++ck) {
        {
            const float cw0 = sWg[sp][0], cw1 = sWg[sp][1], cw2 = sWg[sp][2], cw3 = sWg[sp][3];
            const int   co0 = sOf[sp][0], co1 = sOf[sp][1], co2 = sOf[sp][2], co3 = sOf[sp][3];
            const int   cb  = ck * BK + ssub * 16;
            const float* ib = img;
            #pragma unroll
            for (int h = 0; h < 2; ++h) {
                uint4 ov;
                unsigned* op = (unsigned*)&ov;
                #pragma unroll
                for (int wI = 0; wI < 4; ++wI) {
                    const int c = cb + h * 8 + 2 * wI;
                    const float vlo = cw0*ib[co0 + c*HWPIX] + cw1*ib[co1 + c*HWPIX]
                                    + cw2*ib[co2 + c*HWPIX] + cw3*ib[co3 + c*HWPIX];
                    const float vhi = cw0*ib[co0 + (c+1)*HWPIX] + cw1*ib[co1 + (c+1)*HWPIX]
                                    + cw2*ib[co2 + (c+1)*HWPIX] + cw3*ib[co3 + (c+1)*HWPIX];
                    op[wI] = pack2(vlo, vhi);
                }
                *(uint4*)&sS[sp][ssub * 16 + h * 8] = ov;
            }
        }
        {
            #pragma unroll
            for (int pass = 0; pass < 4; ++pass) {
                const int r = pass * 64 + (tid >> 2);
                const int c = (tid & 3) * 16;
                const float* wr = alw + (size_t)r * C_IMG + ck * BK + c;
                const float4 f0 = *(const float4*)(wr + 0);
                const float4 f1 = *(const float4*)(wr + 4);
                const float4 f2 = *(const float4*)(wr + 8);
                const float4 f3 = *(const float4*)(wr + 12);
                uint4 oa, ob;
                oa.x = pack2(f0.x, f0.y); oa.y = pack2(f0.z, f0.w);
                oa.z = pack2(f1.x, f1.y); oa.w = pack2(f1.z, f1.w);
                ob.x = pack2(f2.x, f2.y); ob.y = pack2(f2.z, f2.w);
                ob.z = pack2(f3.x, f3.y); ob.w = pack2(f3.z, f3.w);
                *(uint4*)&sW[r][c]     = oa;
                *(uint4*)&sW[r][c + 8] = ob;
            }
        }
        __syncthreads();

        #pragma unroll
        for (int kk = 0; kk < 2; ++kk) {
            bf16x8 af[4], bfr[4];
            #pragma unroll
            for (int mt = 0; mt < 4; ++mt)
                af[mt] = *(const bf16x8*)&sS[mt * 16 + l15][kk * 32 + quad * 8];
            #pragma unroll
            for (int nt = 0; nt < 4; ++nt)
                bfr[nt] = *(const bf16x8*)&sW[wid * 64 + nt * 16 + l15][kk * 32 + quad * 8];
            #pragma unroll
            for (int mt = 0; mt < 4; ++mt)
                #pragma unroll
                for (int nt = 0; nt < 4; ++nt)
                    acc[mt][nt] = __builtin_amdgcn_mfma_f32_16x16x32_bf16(
                        af[mt], bfr[nt], acc[mt][nt], 0, 0, 0);
        }
        __syncthreads();
    }

    #pragma unroll
    for (int mt = 0; mt < 4; ++mt) {
        #pragma unroll
        for (int r = 0; r < 4; ++r) {
            const int p = pt0 + mt * 16 + quad * 4 + r;
            if (p < n) {
                #pragma unroll
                for (int nt = 0; nt < 4; ++nt) {
                    const int nc = wid * 64 + nt * 16 + l15;
                    const size_t idx = (size_t)p * C_PT + nc;
                    out[idx] = pf[idx] + alb[nc] + acc[mt][nt][r];
                }
            }
        }
    }
}

extern "C" void kernel_launch(void* const* d_in, const int* in_sizes, int n_in,
                              void* d_out, int out_size, void* d_ws, size_t ws_size,
                              hipStream_t stream) {
    const float* pf      = (const float*)d_in[0];
    const float* centers = (const float*)d_in[1];
    const float* img     = (const float*)d_in[2];
    const float* P2      = (const float*)d_in[3];
    const float* R0      = (const float*)d_in[4];
    const float* Tr      = (const float*)d_in[5];
    const float* alw     = (const float*)d_in[6];
    const float* alb     = (const float*)d_in[7];
    const int*   bidx    = (const int*)d_in[8];
    float*       out     = (float*)d_out;

    const int n  = in_sizes[8];           // 100000 points
    const int bs = in_sizes[3] / 12;      // P2 is (BS,3,4)

    const size_t tpt = (size_t)bs * HWPIX * C_PT * sizeof(unsigned short);
    const size_t tw  = (size_t)C_PT * C_IMG * sizeof(unsigned short);
    const size_t tof = (size_t)n * 16;
    const size_t twg = (size_t)n * 16;
    if (ws_size >= tpt + tw + tof + twg) {
        unsigned short* PT  = (unsigned short*)d_ws;
        unsigned short* wbf = (unsigned short*)((char*)d_ws + tpt);
        u32x4*          poff = (u32x4*)((char*)d_ws + tpt + tw);
        f32x4*          pwgt = (f32x4*)((char*)d_ws + tpt + tw + tof);

        cvt_w_kernel<<<(C_PT * C_IMG / 8) / 256, 256, 0, stream>>>(alw, wbf);
        params_kernel<<<(n + 255) / 256, 256, 0, stream>>>(
            centers, P2, R0, Tr, bidx, poff, pwgt, n);
        proj_kernel<<<bs * (HWPIX / 64), 256, 0, stream>>>(img, wbf, PT);
        point_kernel<<<(n + 31) / 32, 256, 0, stream>>>(
            pf, PT, alb, poff, pwgt, out, n);
    } else {
        const int nblk = (n + MP - 1) / MP;
        fused_fallback_kernel<<<nblk, 256, 0, stream>>>(
            pf, centers, img, P2, R0, Tr, alw, alb, bidx, out, n);
    }
}